// Round 1
// baseline (967.661 us; speedup 1.0000x reference)
//
#include <hip/hip_runtime.h>

#define N_NODES   100000
#define N_EDGES   3200000
#define IN_DIM    128
#define EMB       32
#define NUM_GRAPHS 256

// ---------------------------------------------------------------------------
// Kernel 1: xw = x @ W1   (x: [N,128] fp32, W1: [128,32] fp32 -> xw: [N,32])
// 256 threads = 8 rows x 32 cols. W1 staged in LDS (16 KB). x rows read as
// broadcast float4 (all 32 col-lanes of a row hit the same address -> 1 txn).
// ---------------------------------------------------------------------------
__global__ __launch_bounds__(256) void k_xw(const float* __restrict__ x,
                                            const float* __restrict__ W1,
                                            float* __restrict__ xw) {
    __shared__ float Ws[IN_DIM * EMB];
    for (int i = threadIdx.x; i < IN_DIM * EMB; i += 256) Ws[i] = W1[i];
    __syncthreads();
    int row = blockIdx.x * 8 + (threadIdx.x >> 5);
    int col = threadIdx.x & 31;
    if (row >= N_NODES) return;
    const float4* xr = (const float4*)(x + (size_t)row * IN_DIM);
    float acc = 0.f;
#pragma unroll
    for (int k4 = 0; k4 < IN_DIM / 4; ++k4) {
        float4 xv = xr[k4];
        int k = k4 * 4;
        acc += xv.x * Ws[(k + 0) * EMB + col];
        acc += xv.y * Ws[(k + 1) * EMB + col];
        acc += xv.z * Ws[(k + 2) * EMB + col];
        acc += xv.w * Ws[(k + 3) * EMB + col];
    }
    xw[(size_t)row * EMB + col] = acc;
}

// ---------------------------------------------------------------------------
// Kernel 2: in-degree count (deg[dst] += 1 per edge; +1 self-loop added later)
// ---------------------------------------------------------------------------
__global__ __launch_bounds__(256) void k_deg(const int* __restrict__ ei,
                                             float* __restrict__ deg) {
    int e = blockIdx.x * 256 + threadIdx.x;
    if (e < N_EDGES) atomicAdd(&deg[ei[N_EDGES + e]], 1.0f);
}

// ---------------------------------------------------------------------------
// Kernel 3: dinv = rsqrt(deg+1); agg initialized with self-loop term
// one thread per (node, col)
// ---------------------------------------------------------------------------
__global__ __launch_bounds__(256) void k_selfloop(const float* __restrict__ deg,
                                                  const float* __restrict__ xw,
                                                  float* __restrict__ dinv,
                                                  float* __restrict__ agg) {
    int t = blockIdx.x * 256 + threadIdx.x;
    int i = t >> 5, c = t & 31;
    if (i >= N_NODES) return;
    float d = rsqrtf(deg[i] + 1.0f);
    if (c == 0) dinv[i] = d;
    agg[(size_t)i * EMB + c] = xw[(size_t)i * EMB + c] * d * d;
}

// ---------------------------------------------------------------------------
// Kernel 4: edge scatter — agg[dst] += xw[src] * dinv[src]*dinv[dst]
// one thread per (edge, col); edge indices broadcast across the 32 col-lanes.
// ---------------------------------------------------------------------------
__global__ __launch_bounds__(256) void k_scatter(const int* __restrict__ ei,
                                                 const float* __restrict__ dinv,
                                                 const float* __restrict__ xw,
                                                 float* __restrict__ agg) {
    int t = blockIdx.x * 256 + threadIdx.x;
    int e = t >> 5, c = t & 31;
    if (e >= N_EDGES) return;
    int s = ei[e];
    int d = ei[N_EDGES + e];
    float nrm = dinv[s] * dinv[d];
    atomicAdd(&agg[(size_t)d * EMB + c], xw[(size_t)s * EMB + c] * nrm);
}

// ---------------------------------------------------------------------------
// Kernel 5: h = tanh(agg + b1); pool sums += h per graph; counts per node
// ---------------------------------------------------------------------------
__global__ __launch_bounds__(256) void k_pool(const float* __restrict__ agg,
                                              const float* __restrict__ b1,
                                              const int* __restrict__ batch,
                                              float* __restrict__ sums,
                                              float* __restrict__ counts) {
    int t = blockIdx.x * 256 + threadIdx.x;
    int i = t >> 5, c = t & 31;
    if (i >= N_NODES) return;
    int g = batch[i];
    float h = tanhf(agg[(size_t)i * EMB + c] + b1[c]);
    atomicAdd(&sums[g * EMB + c], h);
    if (c == 0) atomicAdd(&counts[g], 1.0f);
}

// ---------------------------------------------------------------------------
// Kernel 6: out[g] = [sums, means] @ Wout + bout   (G=256, Wout: [64,1])
// ---------------------------------------------------------------------------
__global__ __launch_bounds__(64) void k_out(const float* __restrict__ sums,
                                            const float* __restrict__ counts,
                                            const float* __restrict__ Wout,
                                            const float* __restrict__ bout,
                                            float* __restrict__ out) {
    int g = blockIdx.x * 64 + threadIdx.x;
    if (g >= NUM_GRAPHS) return;
    float inv = 1.0f / fmaxf(counts[g], 1.0f);
    float acc = bout[0];
#pragma unroll
    for (int c = 0; c < EMB; ++c) {
        float s = sums[g * EMB + c];
        acc += s * Wout[c] + s * inv * Wout[EMB + c];
    }
    out[g] = acc;
}

extern "C" void kernel_launch(void* const* d_in, const int* in_sizes, int n_in,
                              void* d_out, int out_size, void* d_ws, size_t ws_size,
                              hipStream_t stream) {
    const float* x     = (const float*)d_in[0];
    const int*   ei    = (const int*)d_in[1];   // [2, E] int32
    const int*   batch = (const int*)d_in[2];   // [N] int32, sorted
    const float* W1    = (const float*)d_in[3];
    const float* b1    = (const float*)d_in[4];
    const float* Wout  = (const float*)d_in[5];
    const float* bout  = (const float*)d_in[6];
    float* out = (float*)d_out;

    // workspace layout (ws is re-poisoned 0xAA before every launch)
    char* ws = (char*)d_ws;
    float* xw   = (float*)ws;  ws += (size_t)N_NODES * EMB * sizeof(float);   // 12.8 MB
    float* agg  = (float*)ws;  ws += (size_t)N_NODES * EMB * sizeof(float);   // 12.8 MB
    float* deg  = (float*)ws;  ws += (size_t)N_NODES * sizeof(float);         // 0.4 MB
    float* dinv = (float*)ws;  ws += (size_t)N_NODES * sizeof(float);         // 0.4 MB
    float* sums = (float*)ws;  ws += (size_t)NUM_GRAPHS * EMB * sizeof(float);// 32 KB
    float* counts = (float*)ws;                                               // 1 KB (contiguous after sums)

    // zero the accumulators (agg is fully written by k_selfloop, no memset needed)
    hipMemsetAsync(deg, 0, (size_t)N_NODES * sizeof(float), stream);
    hipMemsetAsync(sums, 0, (size_t)(NUM_GRAPHS * EMB + NUM_GRAPHS) * sizeof(float), stream);

    k_xw<<<(N_NODES + 7) / 8, 256, 0, stream>>>(x, W1, xw);
    k_deg<<<(N_EDGES + 255) / 256, 256, 0, stream>>>(ei, deg);
    k_selfloop<<<(N_NODES * 32 + 255) / 256, 256, 0, stream>>>(deg, xw, dinv, agg);
    k_scatter<<<(int)(((size_t)N_EDGES * 32 + 255) / 256), 256, 0, stream>>>(ei, dinv, xw, agg);
    k_pool<<<(N_NODES * 32 + 255) / 256, 256, 0, stream>>>(agg, b1, batch, sums, counts);
    k_out<<<(NUM_GRAPHS + 63) / 64, 64, 0, stream>>>(sums, counts, Wout, bout, out);
}

// Round 2
// 683.396 us; speedup vs baseline: 1.4160x; 1.4160x over previous
//
#include <hip/hip_runtime.h>

#define N_NODES    100000
#define N_EDGES    3200000
#define IN_DIM     128
#define EMB        32
#define NUM_GRAPHS 256
#define NBLK       391           // ceil(N_NODES/256) for the scan kernels

// ---------------------------------------------------------------------------
// Kernel 1: xw = x @ W1   (x: [N,128], W1: [128,32] -> xw: [N,32])
// 256 threads = 8 rows x 32 cols; W1 staged in LDS; x read as broadcast float4.
// ---------------------------------------------------------------------------
__global__ __launch_bounds__(256) void k_xw(const float* __restrict__ x,
                                            const float* __restrict__ W1,
                                            float* __restrict__ xw) {
    __shared__ float Ws[IN_DIM * EMB];
    for (int i = threadIdx.x; i < IN_DIM * EMB; i += 256) Ws[i] = W1[i];
    __syncthreads();
    int row = blockIdx.x * 8 + (threadIdx.x >> 5);
    int col = threadIdx.x & 31;
    if (row >= N_NODES) return;
    const float4* xr = (const float4*)(x + (size_t)row * IN_DIM);
    float acc = 0.f;
#pragma unroll
    for (int k4 = 0; k4 < IN_DIM / 4; ++k4) {
        float4 xv = xr[k4];
        int k = k4 * 4;
        acc += xv.x * Ws[(k + 0) * EMB + col];
        acc += xv.y * Ws[(k + 1) * EMB + col];
        acc += xv.z * Ws[(k + 2) * EMB + col];
        acc += xv.w * Ws[(k + 3) * EMB + col];
    }
    xw[(size_t)row * EMB + col] = acc;
}

// ---------------------------------------------------------------------------
// Kernel 2: in-degree (int) per dst
// ---------------------------------------------------------------------------
__global__ __launch_bounds__(256) void k_deg(const int* __restrict__ ei,
                                             int* __restrict__ deg) {
    int e = blockIdx.x * 256 + threadIdx.x;
    if (e < N_EDGES) atomicAdd(&deg[ei[N_EDGES + e]], 1);
}

// ---------------------------------------------------------------------------
// Scan stage 1: per-block sum of deg
// ---------------------------------------------------------------------------
__global__ __launch_bounds__(256) void k_scan1(const int* __restrict__ deg,
                                               int* __restrict__ bsum) {
    int t = threadIdx.x;
    int i = blockIdx.x * 256 + t;
    __shared__ int sd[256];
    sd[t] = (i < N_NODES) ? deg[i] : 0;
    __syncthreads();
    for (int off = 128; off > 0; off >>= 1) {
        if (t < off) sd[t] += sd[t + off];
        __syncthreads();
    }
    if (t == 0) bsum[blockIdx.x] = sd[0];
}

// ---------------------------------------------------------------------------
// Scan stage 2: exclusive scan of the NBLK block sums (one block, in place)
// ---------------------------------------------------------------------------
__global__ __launch_bounds__(512) void k_scan2(int* __restrict__ bsum) {
    int t = threadIdx.x;
    __shared__ int sd[512];
    int v = (t < NBLK) ? bsum[t] : 0;
    sd[t] = v;
    __syncthreads();
    for (int off = 1; off < 512; off <<= 1) {
        int u = (t >= off) ? sd[t - off] : 0;
        __syncthreads();
        sd[t] += u;
        __syncthreads();
    }
    if (t < NBLK) bsum[t] = sd[t] - v;   // exclusive prefix
}

// ---------------------------------------------------------------------------
// Scan stage 3: rowstart[i] = bprefix + block-exclusive-scan(deg); cursor copy;
// dinv[i] = rsqrt(deg+1).  NOTE: cursor aliases deg — safe: each thread reads
// deg[i] before any thread of this block writes cursor[i], ranges are disjoint
// across blocks.
// ---------------------------------------------------------------------------
__global__ __launch_bounds__(256) void k_scan3(const int* __restrict__ deg,
                                               const int* __restrict__ bprefix,
                                               int* __restrict__ rowstart,
                                               int* __restrict__ cursor,
                                               float* __restrict__ dinv) {
    int t = threadIdx.x;
    int i = blockIdx.x * 256 + t;
    int v = (i < N_NODES) ? deg[i] : 0;
    __shared__ int sd[256];
    sd[t] = v;
    __syncthreads();
    for (int off = 1; off < 256; off <<= 1) {
        int u = (t >= off) ? sd[t - off] : 0;
        __syncthreads();
        sd[t] += u;
        __syncthreads();
    }
    if (i < N_NODES) {
        int excl = bprefix[blockIdx.x] + sd[t] - v;
        rowstart[i] = excl;
        cursor[i]   = excl;
        dinv[i]     = rsqrtf((float)v + 1.0f);
    }
    if (i == 0) rowstart[N_NODES] = N_EDGES;
}

// ---------------------------------------------------------------------------
// CSR fill: place each edge's src into its dst's segment (1 atomic per edge)
// ---------------------------------------------------------------------------
__global__ __launch_bounds__(256) void k_fill(const int* __restrict__ ei,
                                              int* __restrict__ cursor,
                                              int* __restrict__ edge_src) {
    int e = blockIdx.x * 256 + threadIdx.x;
    if (e >= N_EDGES) return;
    int s = ei[e];
    int d = ei[N_EDGES + e];
    int pos = atomicAdd(&cursor[d], 1);
    edge_src[pos] = s;
}

// ---------------------------------------------------------------------------
// Fused gather: per node, acc = sum_in xw[s]*dinv[s]; h = tanh((acc+xw[i]*di)*di
// + b1); block-level pool reduction exploiting sorted batch (8 nodes/block).
// 12500 blocks x 8 nodes = exactly N_NODES (no tail guard needed).
// ---------------------------------------------------------------------------
__global__ __launch_bounds__(256) void k_gather(const float* __restrict__ xw,
                                                const float* __restrict__ dinv,
                                                const int* __restrict__ rowstart,
                                                const int* __restrict__ edge_src,
                                                const int* __restrict__ batch,
                                                const float* __restrict__ b1,
                                                float* __restrict__ sums) {
    int r = threadIdx.x >> 5;            // node row within block, 0..7
    int c = threadIdx.x & 31;            // embedding column
    int i = blockIdx.x * 8 + r;
    float di = dinv[i];
    int e0 = rowstart[i], e1 = rowstart[i + 1];
    float acc = 0.f;
    int e = e0;
    for (; e + 1 < e1; e += 2) {         // 2-edge unroll: 2 gathers in flight
        int s0 = edge_src[e];
        int s1 = edge_src[e + 1];
        float d0 = dinv[s0];
        float d1 = dinv[s1];
        acc += xw[s0 * EMB + c] * d0;
        acc += xw[s1 * EMB + c] * d1;
    }
    if (e < e1) {
        int s = edge_src[e];
        acc += xw[s * EMB + c] * dinv[s];
    }
    float h = tanhf((acc + xw[i * EMB + c] * di) * di + b1[c]);

    __shared__ float hs[8][EMB];
    __shared__ int gb[8];
    hs[r][c] = h;
    if (c == 0) gb[r] = batch[i];
    __syncthreads();
    if (threadIdx.x < 32) {
        int cc = threadIdx.x;
        int rr = 0;
        while (rr < 8) {                 // merge runs of equal graph id
            int g0 = gb[rr];
            float a = hs[rr][cc];
            int r2 = rr + 1;
            while (r2 < 8 && gb[r2] == g0) { a += hs[r2][cc]; ++r2; }
            atomicAdd(&sums[g0 * EMB + cc], a);
            rr = r2;
        }
    }
}

// ---------------------------------------------------------------------------
// counts via binary search on sorted batch (no atomics)
// ---------------------------------------------------------------------------
__global__ __launch_bounds__(256) void k_bounds(const int* __restrict__ batch,
                                                float* __restrict__ counts) {
    int g = threadIdx.x;                 // one block of 256
    int lo = 0, hi = N_NODES;
    while (lo < hi) { int m = (lo + hi) >> 1; if (batch[m] < g) lo = m + 1; else hi = m; }
    int a = lo;
    lo = 0; hi = N_NODES;
    int g1 = g + 1;
    while (lo < hi) { int m = (lo + hi) >> 1; if (batch[m] < g1) lo = m + 1; else hi = m; }
    counts[g] = (float)(lo - a);
}

// ---------------------------------------------------------------------------
// head: out[g] = [sums, means] @ Wout + bout
// ---------------------------------------------------------------------------
__global__ __launch_bounds__(64) void k_out(const float* __restrict__ sums,
                                            const float* __restrict__ counts,
                                            const float* __restrict__ Wout,
                                            const float* __restrict__ bout,
                                            float* __restrict__ out) {
    int g = blockIdx.x * 64 + threadIdx.x;
    if (g >= NUM_GRAPHS) return;
    float inv = 1.0f / fmaxf(counts[g], 1.0f);
    float acc = bout[0];
#pragma unroll
    for (int c = 0; c < EMB; ++c) {
        float s = sums[g * EMB + c];
        acc += s * Wout[c] + s * inv * Wout[EMB + c];
    }
    out[g] = acc;
}

extern "C" void kernel_launch(void* const* d_in, const int* in_sizes, int n_in,
                              void* d_out, int out_size, void* d_ws, size_t ws_size,
                              hipStream_t stream) {
    const float* x     = (const float*)d_in[0];
    const int*   ei    = (const int*)d_in[1];   // [2, E]
    const int*   batch = (const int*)d_in[2];   // [N], sorted
    const float* W1    = (const float*)d_in[3];
    const float* b1    = (const float*)d_in[4];
    const float* Wout  = (const float*)d_in[5];
    const float* bout  = (const float*)d_in[6];
    float* out = (float*)d_out;

    // workspace layout (~26.8 MB)
    char* ws = (char*)d_ws;
    float* xw       = (float*)ws; ws += (size_t)N_NODES * EMB * sizeof(float);   // 12.8 MB
    int*   edge_src = (int*)ws;   ws += (size_t)N_EDGES * sizeof(int);           // 12.8 MB
    int*   deg      = (int*)ws;   ws += (size_t)N_NODES * sizeof(int);           // 0.4 MB (aliased as cursor)
    float* dinv     = (float*)ws; ws += (size_t)N_NODES * sizeof(float);         // 0.4 MB
    int*   rowstart = (int*)ws;   ws += (size_t)(N_NODES + 4) * sizeof(int);     // 0.4 MB
    int*   bsum     = (int*)ws;   ws += (size_t)512 * sizeof(int);
    float* sums     = (float*)ws; ws += (size_t)NUM_GRAPHS * EMB * sizeof(float);// 32 KB
    float* counts   = (float*)ws;
    int*   cursor   = deg;  // reuse: k_scan3 converts deg -> cursor in place

    hipMemsetAsync(deg, 0, (size_t)N_NODES * sizeof(int), stream);
    hipMemsetAsync(sums, 0, (size_t)NUM_GRAPHS * EMB * sizeof(float), stream);

    k_xw    <<<(N_NODES + 7) / 8, 256, 0, stream>>>(x, W1, xw);
    k_deg   <<<(N_EDGES + 255) / 256, 256, 0, stream>>>(ei, deg);
    k_scan1 <<<NBLK, 256, 0, stream>>>(deg, bsum);
    k_scan2 <<<1, 512, 0, stream>>>(bsum);
    k_scan3 <<<NBLK, 256, 0, stream>>>(deg, bsum, rowstart, cursor, dinv);
    k_fill  <<<(N_EDGES + 255) / 256, 256, 0, stream>>>(ei, cursor, edge_src);
    k_bounds<<<1, 256, 0, stream>>>(batch, counts);
    k_gather<<<N_NODES / 8, 256, 0, stream>>>(xw, dinv, rowstart, edge_src, batch, b1, sums);
    k_out   <<<(NUM_GRAPHS + 63) / 64, 64, 0, stream>>>(sums, counts, Wout, bout, out);
}

// Round 3
// 324.680 us; speedup vs baseline: 2.9804x; 2.1048x over previous
//
#include <hip/hip_runtime.h>
#include <hip/hip_fp16.h>

#define N_NODES    100000
#define N_EDGES    3200000
#define IN_DIM     128
#define EMB        32
#define NUM_GRAPHS 256

#define FB         512       // coarse buckets (391 used: bucket = dst >> 8)
#define F1_EPB     8192      // edges per fill/hist block
#define F1_BLOCKS  391       // ceil(N_EDGES / F1_EPB)
#define NBUCKETS   391       // ceil(N_NODES / 256)

// ---------------------------------------------------------------------------
// Kernel 1: xw = x @ W1 -> fp16  (x: [N,128], W1: [128,32])
// 256 threads = 8 rows x 32 cols; W1 in LDS; x read as broadcast float4.
// ---------------------------------------------------------------------------
__global__ __launch_bounds__(256) void k_xw(const float* __restrict__ x,
                                            const float* __restrict__ W1,
                                            __half* __restrict__ xwh) {
    __shared__ float Ws[IN_DIM * EMB];
    for (int i = threadIdx.x; i < IN_DIM * EMB; i += 256) Ws[i] = W1[i];
    __syncthreads();
    int row = blockIdx.x * 8 + (threadIdx.x >> 5);
    int col = threadIdx.x & 31;
    if (row >= N_NODES) return;
    const float4* xr = (const float4*)(x + (size_t)row * IN_DIM);
    float acc = 0.f;
#pragma unroll
    for (int k4 = 0; k4 < IN_DIM / 4; ++k4) {
        float4 xv = xr[k4];
        int k = k4 * 4;
        acc += xv.x * Ws[(k + 0) * EMB + col];
        acc += xv.y * Ws[(k + 1) * EMB + col];
        acc += xv.z * Ws[(k + 2) * EMB + col];
        acc += xv.w * Ws[(k + 3) * EMB + col];
    }
    xwh[(size_t)row * EMB + col] = __float2half(acc);
}

// ---------------------------------------------------------------------------
// Coarse histogram: chist[dst>>8] counts (per-block LDS hist, 1 global
// atomic per nonzero (block,bucket) instead of 1 per edge).
// ---------------------------------------------------------------------------
__global__ __launch_bounds__(512) void k_hist1(const int* __restrict__ ei,
                                               int* __restrict__ chist) {
    __shared__ int h[FB];
    int t = threadIdx.x;
    h[t] = 0;
    __syncthreads();
    int e0 = blockIdx.x * F1_EPB;
    for (int k = t; k < F1_EPB; k += 512) {
        int e = e0 + k;
        if (e < N_EDGES) atomicAdd(&h[ei[N_EDGES + e] >> 8], 1);
    }
    __syncthreads();
    if (h[t]) atomicAdd(&chist[t], h[t]);
}

// ---------------------------------------------------------------------------
// Exclusive scan of the 512 coarse counts -> cbase (kept) and gcursor (mutated
// by fill1 reservations). One block of 512.
// ---------------------------------------------------------------------------
__global__ __launch_bounds__(512) void k_scanc(const int* __restrict__ chist,
                                               int* __restrict__ cbase,
                                               int* __restrict__ gcursor) {
    __shared__ int sc[FB];
    int t = threadIdx.x;
    int v = chist[t];
    sc[t] = v;
    __syncthreads();
    for (int off = 1; off < FB; off <<= 1) {
        int u = (t >= off) ? sc[t - off] : 0;
        __syncthreads();
        sc[t] += u;
        __syncthreads();
    }
    int excl = sc[t] - v;
    cbase[t] = excl;
    gcursor[t] = excl;
}

// ---------------------------------------------------------------------------
// Fill pass 1: coarse counting sort with LDS staging -> recs[] grouped by
// coarse bucket. rec = (dst&255)<<24 | src  (src < 2^17). Flush writes are
// contiguous runs (~21 records avg), killing the line-writeback amplification.
// ---------------------------------------------------------------------------
__global__ __launch_bounds__(512) void k_fill1(const int* __restrict__ ei,
                                               int* __restrict__ gcursor,
                                               unsigned int* __restrict__ recs) {
    __shared__ int hist[FB];
    __shared__ int loff[FB];     // block-local exclusive offsets
    __shared__ int base[FB];     // global base reserved for this block
    __shared__ int lcur[FB];
    __shared__ unsigned int lbuf[F1_EPB];   // 32 KB staging
    int t = threadIdx.x;
    hist[t] = 0;
    lcur[t] = 0;
    __syncthreads();
    int e0 = blockIdx.x * F1_EPB;
    // 1) local histogram
    for (int k = t; k < F1_EPB; k += 512) {
        int e = e0 + k;
        if (e < N_EDGES) atomicAdd(&hist[ei[N_EDGES + e] >> 8], 1);
    }
    __syncthreads();
    // 2) local exclusive scan (Hillis-Steele over 512)
    {
        __shared__ int sc[FB];
        int v = hist[t];
        sc[t] = v;
        __syncthreads();
        for (int off = 1; off < FB; off <<= 1) {
            int u = (t >= off) ? sc[t - off] : 0;
            __syncthreads();
            sc[t] += u;
            __syncthreads();
        }
        loff[t] = sc[t] - v;
    }
    // 3) global reservation: one atomic per nonzero (block,bucket)
    if (hist[t]) base[t] = atomicAdd(&gcursor[t], hist[t]);
    __syncthreads();
    // 4) place records into LDS ordered by bucket
    for (int k = t; k < F1_EPB; k += 512) {
        int e = e0 + k;
        if (e < N_EDGES) {
            int s = ei[e];
            int d = ei[N_EDGES + e];
            int b = d >> 8;
            int p = loff[b] + atomicAdd(&lcur[b], 1);
            lbuf[p] = ((unsigned int)(d & 255) << 24) | (unsigned int)s;
        }
    }
    __syncthreads();
    // 5) coalesced flush: entry j belongs to largest b with loff[b] <= j
    int total = loff[FB - 1] + hist[FB - 1];
    for (int j = t; j < total; j += 512) {
        int lo = 0, hi = FB - 1;
        while (lo < hi) { int m = (lo + hi + 1) >> 1; if (loff[m] <= j) lo = m; else hi = m - 1; }
        recs[base[lo] + (j - loff[lo])] = lbuf[j];
    }
}

// ---------------------------------------------------------------------------
// Fill pass 2: one block per coarse bucket. Exact counting sort by dst&255
// inside the bucket's 33 KB window (L2-local scatters -> writeback == payload).
// Also emits rowstart, deg->dinv (replaces the global-atomic k_deg).
// ---------------------------------------------------------------------------
__global__ __launch_bounds__(256) void k_fill2(const unsigned int* __restrict__ recs,
                                               const int* __restrict__ cbase,
                                               const int* __restrict__ chist,
                                               int* __restrict__ edge_src,
                                               int* __restrict__ rowstart,
                                               float* __restrict__ dinv) {
    __shared__ int h2[256], off2[256], cur2[256];
    int t = threadIdx.x;
    int b = blockIdx.x;
    int seg0 = cbase[b];
    int cnt = chist[b];
    h2[t] = 0;
    __syncthreads();
    for (int j = t; j < cnt; j += 256) {
        unsigned int r = recs[seg0 + j];
        atomicAdd(&h2[r >> 24], 1);
    }
    __syncthreads();
    // exclusive scan of 256
    {
        __shared__ int sc[256];
        int v = h2[t];
        sc[t] = v;
        __syncthreads();
        for (int off = 1; off < 256; off <<= 1) {
            int u = (t >= off) ? sc[t - off] : 0;
            __syncthreads();
            sc[t] += u;
            __syncthreads();
        }
        off2[t] = sc[t] - v;
        cur2[t] = sc[t] - v;
    }
    int node = (b << 8) + t;
    if (node < N_NODES) {
        rowstart[node] = seg0 + off2[t];
        dinv[node] = rsqrtf((float)h2[t] + 1.0f);
    }
    if (b == 0 && t == 0) rowstart[N_NODES] = N_EDGES;
    __syncthreads();
    for (int j = t; j < cnt; j += 256) {
        unsigned int r = recs[seg0 + j];
        int p = atomicAdd(&cur2[r >> 24], 1);
        edge_src[seg0 + p] = (int)(r & 0x1FFFF);
    }
}

// ---------------------------------------------------------------------------
// counts via binary search on sorted batch (no atomics)
// ---------------------------------------------------------------------------
__global__ __launch_bounds__(256) void k_bounds(const int* __restrict__ batch,
                                                float* __restrict__ counts) {
    int g = threadIdx.x;
    int lo = 0, hi = N_NODES;
    while (lo < hi) { int m = (lo + hi) >> 1; if (batch[m] < g) lo = m + 1; else hi = m; }
    int a = lo;
    lo = 0; hi = N_NODES;
    int g1 = g + 1;
    while (lo < hi) { int m = (lo + hi) >> 1; if (batch[m] < g1) lo = m + 1; else hi = m; }
    counts[g] = (float)(lo - a);
}

// ---------------------------------------------------------------------------
// Fused gather: per node acc = sum_in xw[s]*dinv[s] (fp16 payload, 4-edge
// unroll), self-loop, tanh, block-level pool into sums (sorted batch).
// ---------------------------------------------------------------------------
__global__ __launch_bounds__(256) void k_gather(const __half* __restrict__ xwh,
                                                const float* __restrict__ dinv,
                                                const int* __restrict__ rowstart,
                                                const int* __restrict__ edge_src,
                                                const int* __restrict__ batch,
                                                const float* __restrict__ b1,
                                                float* __restrict__ sums) {
    int r = threadIdx.x >> 5;
    int c = threadIdx.x & 31;
    int i = blockIdx.x * 8 + r;
    float di = dinv[i];
    int e0 = rowstart[i], e1 = rowstart[i + 1];
    float acc = 0.f;
    int e = e0;
    for (; e + 3 < e1; e += 4) {
        int s0 = edge_src[e], s1 = edge_src[e + 1];
        int s2 = edge_src[e + 2], s3 = edge_src[e + 3];
        float d0 = dinv[s0], d1 = dinv[s1], d2 = dinv[s2], d3 = dinv[s3];
        float v0 = __half2float(xwh[s0 * EMB + c]);
        float v1 = __half2float(xwh[s1 * EMB + c]);
        float v2 = __half2float(xwh[s2 * EMB + c]);
        float v3 = __half2float(xwh[s3 * EMB + c]);
        acc += v0 * d0 + v1 * d1 + v2 * d2 + v3 * d3;
    }
    for (; e < e1; ++e) {
        int s = edge_src[e];
        acc += __half2float(xwh[s * EMB + c]) * dinv[s];
    }
    float h = tanhf((acc + __half2float(xwh[i * EMB + c]) * di) * di + b1[c]);

    __shared__ float hs[8][EMB];
    __shared__ int gb[8];
    hs[r][c] = h;
    if (c == 0) gb[r] = batch[i];
    __syncthreads();
    if (threadIdx.x < 32) {
        int cc = threadIdx.x;
        int rr = 0;
        while (rr < 8) {
            int g0 = gb[rr];
            float a = hs[rr][cc];
            int r2 = rr + 1;
            while (r2 < 8 && gb[r2] == g0) { a += hs[r2][cc]; ++r2; }
            atomicAdd(&sums[g0 * EMB + cc], a);
            rr = r2;
        }
    }
}

// ---------------------------------------------------------------------------
// head: out[g] = [sums, means] @ Wout + bout
// ---------------------------------------------------------------------------
__global__ __launch_bounds__(64) void k_out(const float* __restrict__ sums,
                                            const float* __restrict__ counts,
                                            const float* __restrict__ Wout,
                                            const float* __restrict__ bout,
                                            float* __restrict__ out) {
    int g = blockIdx.x * 64 + threadIdx.x;
    if (g >= NUM_GRAPHS) return;
    float inv = 1.0f / fmaxf(counts[g], 1.0f);
    float acc = bout[0];
#pragma unroll
    for (int c = 0; c < EMB; ++c) {
        float s = sums[g * EMB + c];
        acc += s * Wout[c] + s * inv * Wout[EMB + c];
    }
    out[g] = acc;
}

extern "C" void kernel_launch(void* const* d_in, const int* in_sizes, int n_in,
                              void* d_out, int out_size, void* d_ws, size_t ws_size,
                              hipStream_t stream) {
    const float* x     = (const float*)d_in[0];
    const int*   ei    = (const int*)d_in[1];   // [2, E]
    const int*   batch = (const int*)d_in[2];   // [N], sorted
    const float* W1    = (const float*)d_in[3];
    const float* b1    = (const float*)d_in[4];
    const float* Wout  = (const float*)d_in[5];
    const float* bout  = (const float*)d_in[6];
    float* out = (float*)d_out;

    // workspace (~33.2 MB)
    char* ws = (char*)d_ws;
    __half* xwh         = (__half*)ws;       ws += (size_t)N_NODES * EMB * sizeof(__half);  // 6.4 MB
    unsigned int* recs  = (unsigned int*)ws; ws += (size_t)N_EDGES * sizeof(int);           // 12.8 MB
    int*   edge_src     = (int*)ws;          ws += (size_t)N_EDGES * sizeof(int);           // 12.8 MB
    int*   rowstart     = (int*)ws;          ws += (size_t)(N_NODES + 4) * sizeof(int);     // 0.4 MB
    float* dinv         = (float*)ws;        ws += (size_t)N_NODES * sizeof(float);         // 0.4 MB
    int*   chist        = (int*)ws;          ws += FB * sizeof(int);
    int*   cbase        = (int*)ws;          ws += FB * sizeof(int);
    int*   gcursor      = (int*)ws;          ws += FB * sizeof(int);
    float* sums         = (float*)ws;        ws += (size_t)NUM_GRAPHS * EMB * sizeof(float);
    float* counts       = (float*)ws;

    hipMemsetAsync(chist, 0, FB * sizeof(int), stream);
    hipMemsetAsync(sums, 0, (size_t)NUM_GRAPHS * EMB * sizeof(float), stream);

    k_xw    <<<(N_NODES + 7) / 8, 256, 0, stream>>>(x, W1, xwh);
    k_hist1 <<<F1_BLOCKS, 512, 0, stream>>>(ei, chist);
    k_scanc <<<1, 512, 0, stream>>>(chist, cbase, gcursor);
    k_fill1 <<<F1_BLOCKS, 512, 0, stream>>>(ei, gcursor, recs);
    k_fill2 <<<NBUCKETS, 256, 0, stream>>>(recs, cbase, chist, edge_src, rowstart, dinv);
    k_bounds<<<1, 256, 0, stream>>>(batch, counts);
    k_gather<<<N_NODES / 8, 256, 0, stream>>>(xwh, dinv, rowstart, edge_src, batch, b1, sums);
    k_out   <<<(NUM_GRAPHS + 63) / 64, 64, 0, stream>>>(sums, counts, Wout, bout, out);
}